// Round 4
// baseline (762.311 us; speedup 1.0000x reference)
//
#include <hip/hip_runtime.h>
#include <cstddef>

// HSTU forward. Round 11: resubmit of R10 (container infra failure, no
// kernel-attributable error found on re-audit).
// GEMM 3-buffer counted-vmcnt pipeline (T3+T4):
//  - mfma_gemm: LDS triple-buffer, prefetch depth 2 K-steps, ONE raw
//    s_barrier per K-step with s_waitcnt vmcnt(6) (never 0 mid-loop) ->
//    global->LDS loads stay in flight ACROSS barriers (T4). Stage-issue
//    placed right after the barrier, before ds_read+MFMA (T14 ordering).
//  - GEMM1: 256x128 tile, 512 thr (8 waves 4m x 2n), 144 KB LDS, 512 blocks.
//  - GEMM2: 64x128 tile, 256 thr (4 waves 2x2), 72 KB LDS (2 blocks/CU).
//  - attention/LN/embed/transpose unchanged from Round 9 (746.7 us).
//
// ws layout (90 MB):
//   h32  f32  [8192,512]   @ 0      16 MB   residual stream
//   hbf  bf16 [8192,512]   @ 16 MB   8 MB   GEMM1 A input
//   zbf  bf16 [8192,2048]  @ 24 MB  32 MB   u|q|k|v (GEMM1 out, attn in)
//   ybf  bf16 [8192,512]   @ 56 MB   8 MB   LN1 out (GEMM2 A input)
//   yab  bf16 [8192,512]   @ 64 MB   8 MB   attn out; ALIASED by tbf (GEMM2 out)
//   W1t  bf16 [4,2048,512] @ 80 MB   8 MB   transposed bf16 weights
//   W2t  bf16 [4,512,512]  @ 88 MB   2 MB

#define D_MODEL 512
#define S_LEN 1024
#define NHEADS 8

typedef __bf16 bf16x8 __attribute__((ext_vector_type(8)));
typedef float f32x4 __attribute__((ext_vector_type(4)));
typedef unsigned short us4 __attribute__((ext_vector_type(4)));
typedef unsigned short us8 __attribute__((ext_vector_type(8)));

__device__ __forceinline__ float silu_f(float x) {
  return x / (1.f + __expf(-x));
}
__device__ __forceinline__ unsigned short f2bf(float f) {
  unsigned int u = __float_as_uint(f);
  u += 0x7FFF + ((u >> 16) & 1);   // round-to-nearest-even
  return (unsigned short)(u >> 16);
}
__device__ __forceinline__ float bf2f(unsigned short s) {
  return __uint_as_float(((unsigned int)s) << 16);
}
__device__ __forceinline__ void gll16(const void* g, void* l) {
  __builtin_amdgcn_global_load_lds(
      (const __attribute__((address_space(1))) unsigned int*)g,
      (__attribute__((address_space(3))) unsigned int*)l, 16, 0, 0);
}

// ---------------- embedding + id construction (dual f32/bf16 write) --------
__global__ __launch_bounds__(256) void embed_kernel(
    const int* __restrict__ hist_i, const int* __restrict__ hist_c,
    const int* __restrict__ hlen, const int* __restrict__ tgt_i,
    const int* __restrict__ tgt_c, const float* __restrict__ item_emb,
    const float* __restrict__ cate_emb, const float* __restrict__ seg_emb,
    float* __restrict__ h32, unsigned short* __restrict__ hbf) {
  int bs = blockIdx.x;            // b*1024 + s
  int b = bs >> 10, s = bs & 1023;
  int l = hlen[b];
  int id, cid, sg;
  if (s == l)       { id = tgt_i[b]; cid = tgt_c[b]; sg = 1; }
  else if (s < 1023){ id = hist_i[b * 1023 + s]; cid = hist_c[b * 1023 + s]; sg = 0; }
  else              { id = 0; cid = 0; sg = 0; }   // pad column
  const float* ie = item_emb + (size_t)id * D_MODEL;
  const float* ce = cate_emb + (size_t)cid * D_MODEL;
  const float* se = seg_emb + (size_t)sg * D_MODEL;
  float* hr = h32 + (size_t)bs * D_MODEL;
  unsigned short* hb = hbf + (size_t)bs * D_MODEL;
  for (int d = threadIdx.x; d < D_MODEL; d += 256) {
    float v = ie[d] + ce[d] + se[d];
    hr[d] = v;
    hb[d] = f2bf(v);
  }
}

// ---------------- weight transpose + fp32->bf16: Wt[n][k] = W[k][n] --------
__global__ __launch_bounds__(256) void transpose_kernel(
    const float* __restrict__ W, unsigned short* __restrict__ Wt,
    int K, int N) {
  const int l = blockIdx.z;
  W += (size_t)l * K * N;
  Wt += (size_t)l * K * N;
  const int n0 = blockIdx.x * 64, k0 = blockIdx.y * 64;
  __shared__ float T[64][65];
  const int tid = threadIdx.x;
  const int rr = tid >> 4, cc = (tid & 15) * 4;
#pragma unroll
  for (int p = 0; p < 4; p++) {
    const int r = rr + p * 16;
    const float4 v = *reinterpret_cast<const float4*>(&W[(size_t)(k0 + r) * N + n0 + cc]);
    T[r][cc] = v.x; T[r][cc + 1] = v.y; T[r][cc + 2] = v.z; T[r][cc + 3] = v.w;
  }
  __syncthreads();
#pragma unroll
  for (int p = 0; p < 4; p++) {
    const int r = rr + p * 16;       // n within tile
    us4 o = { f2bf(T[cc + 0][r]), f2bf(T[cc + 1][r]),
              f2bf(T[cc + 2][r]), f2bf(T[cc + 3][r]) };
    *reinterpret_cast<us4*>(&Wt[(size_t)(n0 + r) * K + k0 + cc]) = o;
  }
}

// ---------------- bf16 MFMA GEMM: C = epi(A[M,K] @ Bt[N,K]^T + bias) -------
// TMxTN tile, BK=64, WR*WC waves (wave grid WR rows x WC cols), wave tile
// (TM/WR)x(TN/WC). LDS: As/Bs [3][rows][64] bf16 TRIPLE-buffered,
// xor-swizzled 8-elem chunks.
// K-loop (T3+T4): prologue stages tiles k0=0,64. Each iter:
//   s_waitcnt vmcnt(6)   -- current tile landed; next tile's 6 loads stay
//                           in flight ACROSS the barrier (counted, not 0)
//   s_barrier            -- raw: no lgk/vm drain beyond the explicit wait
//   stage(k0+128) -> buf[(step+2)%3]   (disjoint from cur & next buffers;
//                    its prior readers finished at iter step-1, guaranteed
//                    by THIS barrier)
//   ds_read + MFMA from buf[step%3]  (compiler inserts fine lgkmcnt)
// Hazard audit: reads of buf[x] at iter s complete before iter s's trailing
// MFMAs (lgkmcnt-enforced), which precede the next barrier in program order;
// stage into buf[x] reoccurs earliest at iter s+1 after that barrier. OK.
// SWZ=1: 1D grid, XCD-aware decode (id&7 = XCD; A-stripe + B stay in L2).
template <int TM, int TN, int WR, int WC, int SWZ, int EPI_SILU, typename OutT>
__global__ __launch_bounds__(WR * WC * 64) void mfma_gemm(
    const unsigned short* __restrict__ A, const unsigned short* __restrict__ Bt,
    const float* __restrict__ bias, OutT* __restrict__ C,
    int M, int N, int K) {
  constexpr int NT = WR * WC * 64;            // threads
  constexpr int WM = TM / WR, WN = TN / WC;   // wave tile
  constexpr int MI = WM / 16, NI = WN / 16;   // 16x16 tiles per wave
  static_assert((TM + TN) * 8 / NT == 6, "vmcnt literal assumes 6 loads/stage");
  __shared__ unsigned short As[3][TM * 64];
  __shared__ unsigned short Bs[3][TN * 64];
  const int tid = threadIdx.x;
  const int w = tid >> 6, lane = tid & 63, lm = lane & 15, quad = lane >> 4;
  const int wm = w % WR, wn = w / WR;
  int m0, n0;
  if (SWZ) {
    // xcd = id&7 owns a contiguous stripe of m-blocks; n varies within xcd
    const int id = blockIdx.x;
    const int xcd = id & 7, j = id >> 3;
    const int mPerX = (M / TM) >> 3;
    m0 = (xcd * mPerX + (j % mPerX)) * TM;
    n0 = (j / mPerX) * TN;
  } else {
    m0 = blockIdx.y * TM;
    n0 = blockIdx.x * TN;
  }

  f32x4 acc[MI][NI] = {};

  auto stage = [&](int buf, int k0) {
#pragma unroll
    for (int p = 0; p < TM * 8 / NT; p++) {
      const int g = p * NT + tid;          // 16B chunk id
      const int r = g >> 3;                // tile row
      const int lc = (g & 7) ^ (r & 7);    // logical k-chunk for this phys slot
      gll16(A + (size_t)(m0 + r) * K + k0 + lc * 8, &As[buf][g * 8]);
    }
#pragma unroll
    for (int p = 0; p < TN * 8 / NT; p++) {
      const int g = p * NT + tid;
      const int r = g >> 3;
      const int lc = (g & 7) ^ (r & 7);
      gll16(Bt + (size_t)(n0 + r) * K + k0 + lc * 8, &Bs[buf][g * 8]);
    }
  };

  stage(0, 0);
  if (64 < K) stage(1, 64);
  int cur = 0, nxt = 2;

  for (int k0 = 0; k0 < K; k0 += 64) {
    if (k0 + 64 < K)
      asm volatile("s_waitcnt vmcnt(6)" ::: "memory");   // cur landed; next in flight
    else
      asm volatile("s_waitcnt vmcnt(0)" ::: "memory");   // tail: drain last stage
    __builtin_amdgcn_s_barrier();
    __builtin_amdgcn_sched_barrier(0);
    if (k0 + 128 < K) stage(nxt, k0 + 128);   // issued early; lands under MFMA

    // ---- compute current tile: 2 k-halves of 32 ----
#pragma unroll
    for (int ki = 0; ki < 2; ki++) {
      bf16x8 af[MI], bfr[NI];
#pragma unroll
      for (int mi = 0; mi < MI; mi++) {
        const int r = wm * WM + mi * 16 + lm;
        const int p = (ki * 4 + quad) ^ (lm & 7);
        af[mi] = *reinterpret_cast<const bf16x8*>(&As[cur][r * 64 + p * 8]);
      }
#pragma unroll
      for (int ni = 0; ni < NI; ni++) {
        const int r = wn * WN + ni * 16 + lm;
        const int p = (ki * 4 + quad) ^ (lm & 7);
        bfr[ni] = *reinterpret_cast<const bf16x8*>(&Bs[cur][r * 64 + p * 8]);
      }
      __builtin_amdgcn_s_setprio(1);
#pragma unroll
      for (int mi = 0; mi < MI; mi++)
#pragma unroll
        for (int ni = 0; ni < NI; ni++)
          acc[mi][ni] = __builtin_amdgcn_mfma_f32_16x16x32_bf16(
              af[mi], bfr[ni], acc[mi][ni], 0, 0, 0);
      __builtin_amdgcn_s_setprio(0);
    }
    cur = (cur == 2) ? 0 : cur + 1;
    nxt = (nxt == 2) ? 0 : nxt + 1;
  }

  // ---- epilogue: bias (+silu), C-layout col=lm, row=quad*4+reg ----
#pragma unroll
  for (int ni = 0; ni < NI; ni++) {
    const int n = n0 + wn * WN + ni * 16 + lm;
    const float bv = bias[n];
#pragma unroll
    for (int mi = 0; mi < MI; mi++) {
      const int mbase = m0 + wm * WM + mi * 16 + quad * 4;
#pragma unroll
      for (int reg = 0; reg < 4; reg++) {
        float v = acc[mi][ni][reg] + bv;
        if (EPI_SILU) v = silu_f(v);
        if constexpr (sizeof(OutT) == 2)
          C[(size_t)(mbase + reg) * N + n] = f2bf(v);
        else
          C[(size_t)(mbase + reg) * N + n] = v;
      }
    }
  }
}

// ---------------- fused causal silu-attention, S^T layout, paired qt -------
// att = silu(q k^T + posw[2047+t-s]) * (t<=s);  y = (att @ v) * u
// z row layout (bf16): [u(512) | q(512) | k(512) | v(512)].
// Block: (qt-pair, head, b). Processes q64 tiles qt=blockIdx.x and 15-qt:
// kt-units = (qtA+1)+(qtB+1) = 17 for every block -> perfect balance.
// S^T trick: compute S^T = K Q^T (A=K rows t, B=Q rows s). C-layout gives
// lane (quad,lm): t = tt*16+quad*4+i, s = w*16+lm -> 4 t-consecutive P values
// per lane => us4 ds_write_b64 into Ps[s][t]; PV A-frag = ds_read_b128.
// Q is kept in registers (B-operand frags loaded from global once per tile).
//
// Pipeline: Ks/Vt/bias double-buffered; per kt exactly ONE barrier:
//   [LDS-write buf[kt&1] from regs] -> barrier -> [issue kt+1 global loads
//   into regs] -> [compute from buf[kt&1]].
#define LDR 72   // LDS row stride in u16 (144 B, 16B-aligned, bank-spread)
__global__ __launch_bounds__(256) void attn_kernel(
    const unsigned short* __restrict__ z, const float* __restrict__ posw,
    unsigned short* __restrict__ y) {
  const int hh = blockIdx.y, b = blockIdx.z;
  __shared__ alignas(16) unsigned short Ks[2 * 64 * LDR];
  __shared__ alignas(16) unsigned short Vt[2 * 64 * LDR];
  __shared__ alignas(16) unsigned short Ps[64 * LDR];
  __shared__ float bias_s[2][128];
  const unsigned short* zb = z + (size_t)b * S_LEN * 2048;
  const int tid = threadIdx.x;
  const int w = tid >> 6, lane = tid & 63, lm = lane & 15, quad = lane >> 4;

  // per-thread staging geometry (tid-only, hoisted out of the loops)
  const int kr0r = tid >> 3, kr0c = (tid & 7) * 8;            // K chunk 0
  const int kr1r = (256 + tid) >> 3, kr1c = (tid & 7) * 8;    // K chunk 1
  const int vt = (tid >> 4) * 4, vd = (tid & 15) * 4;         // V 4x4 block
  const int vtb = vt >> 3, vti = vt & 7;

#pragma unroll
  for (int phase = 0; phase < 2; phase++) {
    const int qt = phase == 0 ? (int)blockIdx.x : 15 - (int)blockIdx.x;
    const int s0 = qt * 64;
    const int srow = s0 + w * 16 + lm;   // this lane's q row (as B-operand n)

    // ---- Q fragments in registers (B-operand): Q[srow][ki*32+quad*8 ..+8] --
    const bf16x8 qb0 = *reinterpret_cast<const bf16x8*>(
        zb + (size_t)srow * 2048 + 512 + hh * 64 + quad * 8);
    const bf16x8 qb1 = *reinterpret_cast<const bf16x8*>(
        zb + (size_t)srow * 2048 + 512 + hh * 64 + 32 + quad * 8);

    f32x4 O[4] = {};   // O[s 16][d 64] per wave; col=d-in-tile, row=quad*4+reg

    // staging registers (K tile 2x16B, V 4x4 block, bias scalar)
    us8 kr0, kr1;
    us4 vr0, vr1, vr2, vr3;
    float br = 0.f;

    auto load_stage = [&](int kt) {
      const int t0 = kt * 64;
      kr0 = *reinterpret_cast<const us8*>(
          zb + (size_t)(t0 + kr0r) * 2048 + 1024 + hh * 64 + kr0c);
      kr1 = *reinterpret_cast<const us8*>(
          zb + (size_t)(t0 + kr1r) * 2048 + 1024 + hh * 64 + kr1c);
      vr0 = *reinterpret_cast<const us4*>(
          zb + (size_t)(t0 + vt + 0) * 2048 + 1536 + hh * 64 + vd);
      vr1 = *reinterpret_cast<const us4*>(
          zb + (size_t)(t0 + vt + 1) * 2048 + 1536 + hh * 64 + vd);
      vr2 = *reinterpret_cast<const us4*>(
          zb + (size_t)(t0 + vt + 2) * 2048 + 1536 + hh * 64 + vd);
      vr3 = *reinterpret_cast<const us4*>(
          zb + (size_t)(t0 + vt + 3) * 2048 + 1536 + hh * 64 + vd);
      if (tid < 128) br = posw[2047 + t0 - s0 - 63 + tid];
    };

    auto write_stage = [&](int cur) {
      unsigned short* KsC = Ks + cur * (64 * LDR);
      unsigned short* VtC = Vt + cur * (64 * LDR);
      *reinterpret_cast<us8*>(&KsC[kr0r * LDR + kr0c]) = kr0;
      *reinterpret_cast<us8*>(&KsC[kr1r * LDR + kr1c]) = kr1;
      unsigned short c[4][4];
      c[0][0] = vr0.x; c[0][1] = vr0.y; c[0][2] = vr0.z; c[0][3] = vr0.w;
      c[1][0] = vr1.x; c[1][1] = vr1.y; c[1][2] = vr1.z; c[1][3] = vr1.w;
      c[2][0] = vr2.x; c[2][1] = vr2.y; c[2][2] = vr2.z; c[2][3] = vr2.w;
      c[3][0] = vr3.x; c[3][1] = vr3.y; c[3][2] = vr3.z; c[3][3] = vr3.w;
#pragma unroll
      for (int j = 0; j < 4; j++) {
        const int dd = vd + j;
        us4 o = { c[0][j], c[1][j], c[2][j], c[3][j] };
        *reinterpret_cast<us4*>(&VtC[dd * LDR + ((vtb ^ (dd & 7)) << 3) + vti]) = o;
      }
      if (tid < 128) bias_s[cur][tid] = br;
    };

    load_stage(0);
    __syncthreads();   // phase seam: previous phase's buf readers done

    for (int kt = 0; kt <= qt; kt++) {
      const int cur = kt & 1;
      write_stage(cur);
      __syncthreads();                 // the ONLY barrier per kt
      if (kt < qt) load_stage(kt + 1); // latency hides under compute

      const unsigned short* KsC = Ks + cur * (64 * LDR);
      const unsigned short* VtC = Vt + cur * (64 * LDR);
      const int t0 = kt * 64;

      // ---- S^T = K Q^T : 4 t-tiles x (16 s-cols per wave) ----
#pragma unroll
      for (int tt = 0; tt < 4; tt++) {
        const bf16x8 ka0 = *reinterpret_cast<const bf16x8*>(
            &KsC[(tt * 16 + lm) * LDR + quad * 8]);
        const bf16x8 ka1 = *reinterpret_cast<const bf16x8*>(
            &KsC[(tt * 16 + lm) * LDR + 32 + quad * 8]);
        f32x4 st = {};
        __builtin_amdgcn_s_setprio(1);
        st = __builtin_amdgcn_mfma_f32_16x16x32_bf16(ka0, qb0, st, 0, 0, 0);
        st = __builtin_amdgcn_mfma_f32_16x16x32_bf16(ka1, qb1, st, 0, 0, 0);
        __builtin_amdgcn_s_setprio(0);
        // lane holds t = t0 + tt*16 + quad*4 + i,  s = srow
        const int bbase = 63 + tt * 16 + quad * 4 - w * 16 - lm;  // + i
        const int tq = t0 + tt * 16 + quad * 4;
        us4 pv;
        unsigned short* pp = (unsigned short*)&pv;
#pragma unroll
        for (int i = 0; i < 4; i++) {
          const float x = st[i] + bias_s[cur][bbase + i];
          const float val = (tq + i <= srow) ? silu_f(x) : 0.f;
          pp[i] = f2bf(val);
        }
        // Ps[s][t]: wave-private rows [w*16, w*16+16)
        *reinterpret_cast<us4*>(&Ps[(w * 16 + lm) * LDR + tt * 16 + quad * 4]) = pv;
      }

      // ---- O += P V  (A = Ps stripe, B = Vt) ----
      const bf16x8 pa0 = *reinterpret_cast<const bf16x8*>(
          &Ps[(w * 16 + lm) * LDR + quad * 8]);
      const bf16x8 pa1 = *reinterpret_cast<const bf16x8*>(
          &Ps[(w * 16 + lm) * LDR + 32 + quad * 8]);
#pragma unroll
      for (int ct = 0; ct < 4; ct++) {
        const int d = ct * 16 + lm;
        const bf16x8 vb0 = *reinterpret_cast<const bf16x8*>(
            &VtC[d * LDR + ((quad ^ (d & 7)) << 3)]);            // tb=quad
        const bf16x8 vb1 = *reinterpret_cast<const bf16x8*>(
            &VtC[d * LDR + (((4 + quad) ^ (d & 7)) << 3)]);      // tb=4+quad
        __builtin_amdgcn_s_setprio(1);
        O[ct] = __builtin_amdgcn_mfma_f32_16x16x32_bf16(pa0, vb0, O[ct], 0, 0, 0);
        O[ct] = __builtin_amdgcn_mfma_f32_16x16x32_bf16(pa1, vb1, O[ct], 0, 0, 0);
        __builtin_amdgcn_s_setprio(0);
      }
    }

    // ---- epilogue: y = bf16(O * u) ----
    {
      const int sbase = s0 + w * 16 + quad * 4;
#pragma unroll
      for (int ct = 0; ct < 4; ct++) {
        const int d = ct * 16 + lm;
#pragma unroll
        for (int i = 0; i < 4; i++) {
          const int sg = sbase + i;
          const float u = bf2f(zb[(size_t)sg * 2048 + hh * 64 + d]);
          y[((size_t)(b * S_LEN + sg)) * D_MODEL + hh * 64 + d] = f2bf(O[ct][i] * u);
        }
      }
    }
  }
}

// ---------------- layer norm: one wave per row, templated input ------------
template <typename XT>
__global__ __launch_bounds__(256) void ln_kernel(
    const XT* __restrict__ x, const float* __restrict__ res,
    const float* __restrict__ w, const float* __restrict__ bb,
    float* __restrict__ o32, unsigned short* __restrict__ obf) {
  const int wv = threadIdx.x >> 6, lane = threadIdx.x & 63;
  const size_t row = blockIdx.x * 4 + wv;
  const int c0 = lane * 8;
  float v[8];
  if constexpr (sizeof(XT) == 2) {
    const us8 u = *reinterpret_cast<const us8*>(&x[row * D_MODEL + c0]);
#pragma unroll
    for (int i = 0; i < 8; i++) v[i] = bf2f(u[i]);
  } else {
    const float4 a = *reinterpret_cast<const float4*>(&x[row * D_MODEL + c0]);
    const float4 c = *reinterpret_cast<const float4*>(&x[row * D_MODEL + c0 + 4]);
    v[0] = a.x; v[1] = a.y; v[2] = a.z; v[3] = a.w;
    v[4] = c.x; v[5] = c.y; v[6] = c.z; v[7] = c.w;
  }
  if (res) {
    const float4 r0 = *reinterpret_cast<const float4*>(&res[row * D_MODEL + c0]);
    const float4 r1 = *reinterpret_cast<const float4*>(&res[row * D_MODEL + c0 + 4]);
    v[0] += r0.x; v[1] += r0.y; v[2] += r0.z; v[3] += r0.w;
    v[4] += r1.x; v[5] += r1.y; v[6] += r1.z; v[7] += r1.w;
  }
  float s = 0.f, ss = 0.f;
#pragma unroll
  for (int i = 0; i < 8; i++) { s += v[i]; ss += v[i] * v[i]; }
#pragma unroll
  for (int off = 32; off; off >>= 1) {
    s += __shfl_down(s, off, 64);
    ss += __shfl_down(ss, off, 64);
  }
  s = __shfl(s, 0, 64);
  ss = __shfl(ss, 0, 64);
  const float mu = s * (1.f / D_MODEL);
  const float rstd = rsqrtf(ss * (1.f / D_MODEL) - mu * mu + 1e-5f);
  const float4 w0 = *reinterpret_cast<const float4*>(&w[c0]);
  const float4 w1 = *reinterpret_cast<const float4*>(&w[c0 + 4]);
  const float4 b0 = *reinterpret_cast<const float4*>(&bb[c0]);
  const float4 b1 = *reinterpret_cast<const float4*>(&bb[c0 + 4]);
  float r[8];
  r[0] = (v[0] - mu) * rstd * w0.x + b0.x;
  r[1] = (v[1] - mu) * rstd * w0.y + b0.y;
  r[2] = (v[2] - mu) * rstd * w0.z + b0.z;
  r[3] = (v[3] - mu) * rstd * w0.w + b0.w;
  r[4] = (v[4] - mu) * rstd * w1.x + b1.x;
  r[5] = (v[5] - mu) * rstd * w1.y + b1.y;
  r[6] = (v[6] - mu) * rstd * w1.z + b1.z;
  r[7] = (v[7] - mu) * rstd * w1.w + b1.w;
  if (o32) {
    *reinterpret_cast<float4*>(&o32[row * D_MODEL + c0]) = make_float4(r[0], r[1], r[2], r[3]);
    *reinterpret_cast<float4*>(&o32[row * D_MODEL + c0 + 4]) = make_float4(r[4], r[5], r[6], r[7]);
  }
  if (obf) {
    us8 q = { f2bf(r[0]), f2bf(r[1]), f2bf(r[2]), f2bf(r[3]),
              f2bf(r[4]), f2bf(r[5]), f2bf(r[6]), f2bf(r[7]) };
    *reinterpret_cast<us8*>(&obf[row * D_MODEL + c0]) = q;
  }
}

extern "C" void kernel_launch(void* const* d_in, const int* in_sizes, int n_in,
                              void* d_out, int out_size, void* d_ws, size_t ws_size,
                              hipStream_t stream) {
  const int* hist_i = (const int*)d_in[0];
  const int* hist_c = (const int*)d_in[1];
  const int* hlen   = (const int*)d_in[2];
  const int* tgt_i  = (const int*)d_in[3];
  const int* tgt_c  = (const int*)d_in[4];
  const float* item_emb = (const float*)d_in[5];
  const float* cate_emb = (const float*)d_in[6];
  const float* seg_emb  = (const float*)d_in[7];
  const float* W1   = (const float*)d_in[8];    // [4,512,2048]
  const float* b1   = (const float*)d_in[9];    // [4,2048]
  const float* W2   = (const float*)d_in[10];   // [4,512,512]
  const float* b2   = (const float*)d_in[11];   // [4,512]
  const float* ln1w = (const float*)d_in[12];
  const float* ln1b = (const float*)d_in[13];
  const float* ln2w = (const float*)d_in[14];
  const float* ln2b = (const float*)d_in[15];
  const float* posw = (const float*)d_in[16];   // [4,4095]
  const float* lnfw = (const float*)d_in[17];
  const float* lnfb = (const float*)d_in[18];
  float* out = (float*)d_out;

  char* ws = (char*)d_ws;
  float*          h32 = (float*)(ws);                         // 16 MB
  unsigned short* hbf = (unsigned short*)(ws + (16u << 20));  // 8 MB
  unsigned short* zbf = (unsigned short*)(ws + (24u << 20));  // 32 MB
  unsigned short* ybf = (unsigned short*)(ws + (56u << 20));  // 8 MB
  unsigned short* yab = (unsigned short*)(ws + (64u << 20));  // 8 MB (attn out)
  unsigned short* tbf = yab;                                  // alias: yab dead after LN1
  unsigned short* W1t = (unsigned short*)(ws + (80u << 20));  // 8 MB
  unsigned short* W2t = (unsigned short*)(ws + (88u << 20));  // 2 MB

  const int ROWS = 8 * S_LEN;  // 8192

  transpose_kernel<<<dim3(2048 / 64, 512 / 64, 4), 256, 0, stream>>>(W1, W1t, 512, 2048);
  transpose_kernel<<<dim3(512 / 64, 512 / 64, 4), 256, 0, stream>>>(W2, W2t, 512, 512);
  embed_kernel<<<ROWS, 256, 0, stream>>>(hist_i, hist_c, hlen, tgt_i, tgt_c,
                                         item_emb, cate_emb, seg_emb, h32, hbf);
  for (int l = 0; l < 4; l++) {
    // zbf = silu(h @ W1[l] + b1[l])   [8192, 2048] bf16
    // 256x128 tile, 8 waves, 3-buf counted-vmcnt, XCD swizzle; 512 blocks.
    mfma_gemm<256, 128, 4, 2, 1, 1, unsigned short><<<512, 512, 0, stream>>>(
        hbf, W1t + (size_t)l * 2048 * 512, b1 + (size_t)l * 2048, zbf, ROWS, 2048, 512);
    // yab = bf16((silu-att @ v) * u)  [8192, 512]; paired qt, 512 blocks
    attn_kernel<<<dim3(8, NHEADS, 8), 256, 0, stream>>>(
        zbf, posw + (size_t)l * 4095, yab);
    // ybf = LN1(yab)  (bf16 in, bf16 out)
    ln_kernel<unsigned short><<<ROWS / 4, 256, 0, stream>>>(
        yab, nullptr, ln1w + l * 512, ln1b + l * 512, nullptr, ybf);
    // tbf = bf16(ybf @ W2[l] + b2[l])  (aliases yab; yab dead after LN1)
    // 64x128 tile, 4 waves, 3-buf counted-vmcnt (72 KB LDS -> 2 blocks/CU).
    mfma_gemm<64, 128, 2, 2, 0, 0, unsigned short><<<dim3(512 / 128, ROWS / 64), 256, 0, stream>>>(
        ybf, W2t + (size_t)l * 512 * 512, b2 + (size_t)l * 512, tbf, ROWS, 512, 512);
    // h = LN2(tbf + h)  (f32 + bf16 out)
    ln_kernel<unsigned short><<<ROWS / 4, 256, 0, stream>>>(
        tbf, h32, ln2w + l * 512, ln2b + l * 512, h32, hbf);
  }
  // out = LNf(h)
  ln_kernel<float><<<ROWS / 4, 256, 0, stream>>>(h32, nullptr, lnfw, lnfb, out, nullptr);
}

// Round 5
// 744.375 us; speedup vs baseline: 1.0241x; 1.0241x over previous
//
#include <hip/hip_runtime.h>
#include <cstddef>

// HSTU forward. Round 12: revert to R9-proven 2-phase dbuf GEMM (R10/R11's
// 3-buf 144KB-LDS pipeline regressed: 1 block/CU lost cross-block overlap).
// Single variable vs R9: GEMM1 128x128 tile now 8 waves/block (512 thr,
// wave tile 64x32) -> 2 blocks/CU * 8 waves = 4 waves/SIMD (was 2) for
// better hiding of the per-K-step barrier drain. LDS unchanged 64 KB.
// GEMM2 / attention / LN / embed / transpose identical to R9 (746.7 us).
//
// ws layout (90 MB):
//   h32  f32  [8192,512]   @ 0      16 MB   residual stream
//   hbf  bf16 [8192,512]   @ 16 MB   8 MB   GEMM1 A input
//   zbf  bf16 [8192,2048]  @ 24 MB  32 MB   u|q|k|v (GEMM1 out, attn in)
//   ybf  bf16 [8192,512]   @ 56 MB   8 MB   LN1 out (GEMM2 A input)
//   yab  bf16 [8192,512]   @ 64 MB   8 MB   attn out; ALIASED by tbf (GEMM2 out)
//   W1t  bf16 [4,2048,512] @ 80 MB   8 MB   transposed bf16 weights
//   W2t  bf16 [4,512,512]  @ 88 MB   2 MB

#define D_MODEL 512
#define S_LEN 1024
#define NHEADS 8

typedef __bf16 bf16x8 __attribute__((ext_vector_type(8)));
typedef float f32x4 __attribute__((ext_vector_type(4)));
typedef unsigned short us4 __attribute__((ext_vector_type(4)));
typedef unsigned short us8 __attribute__((ext_vector_type(8)));

__device__ __forceinline__ float silu_f(float x) {
  return x / (1.f + __expf(-x));
}
__device__ __forceinline__ unsigned short f2bf(float f) {
  unsigned int u = __float_as_uint(f);
  u += 0x7FFF + ((u >> 16) & 1);   // round-to-nearest-even
  return (unsigned short)(u >> 16);
}
__device__ __forceinline__ float bf2f(unsigned short s) {
  return __uint_as_float(((unsigned int)s) << 16);
}
__device__ __forceinline__ void gll16(const void* g, void* l) {
  __builtin_amdgcn_global_load_lds(
      (const __attribute__((address_space(1))) unsigned int*)g,
      (__attribute__((address_space(3))) unsigned int*)l, 16, 0, 0);
}

// ---------------- embedding + id construction (dual f32/bf16 write) --------
__global__ __launch_bounds__(256) void embed_kernel(
    const int* __restrict__ hist_i, const int* __restrict__ hist_c,
    const int* __restrict__ hlen, const int* __restrict__ tgt_i,
    const int* __restrict__ tgt_c, const float* __restrict__ item_emb,
    const float* __restrict__ cate_emb, const float* __restrict__ seg_emb,
    float* __restrict__ h32, unsigned short* __restrict__ hbf) {
  int bs = blockIdx.x;            // b*1024 + s
  int b = bs >> 10, s = bs & 1023;
  int l = hlen[b];
  int id, cid, sg;
  if (s == l)       { id = tgt_i[b]; cid = tgt_c[b]; sg = 1; }
  else if (s < 1023){ id = hist_i[b * 1023 + s]; cid = hist_c[b * 1023 + s]; sg = 0; }
  else              { id = 0; cid = 0; sg = 0; }   // pad column
  const float* ie = item_emb + (size_t)id * D_MODEL;
  const float* ce = cate_emb + (size_t)cid * D_MODEL;
  const float* se = seg_emb + (size_t)sg * D_MODEL;
  float* hr = h32 + (size_t)bs * D_MODEL;
  unsigned short* hb = hbf + (size_t)bs * D_MODEL;
  for (int d = threadIdx.x; d < D_MODEL; d += 256) {
    float v = ie[d] + ce[d] + se[d];
    hr[d] = v;
    hb[d] = f2bf(v);
  }
}

// ---------------- weight transpose + fp32->bf16: Wt[n][k] = W[k][n] --------
__global__ __launch_bounds__(256) void transpose_kernel(
    const float* __restrict__ W, unsigned short* __restrict__ Wt,
    int K, int N) {
  const int l = blockIdx.z;
  W += (size_t)l * K * N;
  Wt += (size_t)l * K * N;
  const int n0 = blockIdx.x * 64, k0 = blockIdx.y * 64;
  __shared__ float T[64][65];
  const int tid = threadIdx.x;
  const int rr = tid >> 4, cc = (tid & 15) * 4;
#pragma unroll
  for (int p = 0; p < 4; p++) {
    const int r = rr + p * 16;
    const float4 v = *reinterpret_cast<const float4*>(&W[(size_t)(k0 + r) * N + n0 + cc]);
    T[r][cc] = v.x; T[r][cc + 1] = v.y; T[r][cc + 2] = v.z; T[r][cc + 3] = v.w;
  }
  __syncthreads();
#pragma unroll
  for (int p = 0; p < 4; p++) {
    const int r = rr + p * 16;       // n within tile
    us4 o = { f2bf(T[cc + 0][r]), f2bf(T[cc + 1][r]),
              f2bf(T[cc + 2][r]), f2bf(T[cc + 3][r]) };
    *reinterpret_cast<us4*>(&Wt[(size_t)(n0 + r) * K + k0 + cc]) = o;
  }
}

// ---------------- bf16 MFMA GEMM: C = epi(A[M,K] @ Bt[N,K]^T + bias) -------
// TMxTN tile, BK=64, WR*WC waves (wave grid WR rows x WC cols), wave tile
// (TM/WR)x(TN/WC). LDS: As/Bs [2][rows][64] bf16 double-buffered,
// xor-swizzled 8-elem chunks.
// 2-phase pipeline (R9-proven): prefetch K-step k+1 into buf^1 BEFORE
// computing buf, single __syncthreads per K-step (its implicit vmcnt(0)
// drain lands after the MFMA block -> global->LDS latency hides under
// compute; cross-block TLP covers the rest).
// SWZ=1: 1D grid, XCD-aware decode (id&7 = XCD; A-stripe + B stay in L2).
template <int TM, int TN, int WR, int WC, int SWZ, int EPI_SILU, typename OutT>
__global__ __launch_bounds__(WR * WC * 64) void mfma_gemm(
    const unsigned short* __restrict__ A, const unsigned short* __restrict__ Bt,
    const float* __restrict__ bias, OutT* __restrict__ C,
    int M, int N, int K) {
  constexpr int NT = WR * WC * 64;            // threads
  constexpr int WM = TM / WR, WN = TN / WC;   // wave tile
  constexpr int MI = WM / 16, NI = WN / 16;   // 16x16 tiles per wave
  __shared__ unsigned short As[2][TM * 64];
  __shared__ unsigned short Bs[2][TN * 64];
  const int tid = threadIdx.x;
  const int w = tid >> 6, lane = tid & 63, lm = lane & 15, quad = lane >> 4;
  const int wm = w % WR, wn = w / WR;
  int m0, n0;
  if (SWZ) {
    // xcd = id&7 owns a contiguous stripe of m-blocks; n varies within xcd
    const int id = blockIdx.x;
    const int xcd = id & 7, j = id >> 3;
    const int mPerX = (M / TM) >> 3;
    m0 = (xcd * mPerX + (j % mPerX)) * TM;
    n0 = (j / mPerX) * TN;
  } else {
    m0 = blockIdx.y * TM;
    n0 = blockIdx.x * TN;
  }

  f32x4 acc[MI][NI] = {};

  auto stage = [&](int buf, int k0) {
#pragma unroll
    for (int p = 0; p < TM * 8 / NT; p++) {
      const int g = p * NT + tid;          // 16B chunk id
      const int r = g >> 3;                // tile row
      const int lc = (g & 7) ^ (r & 7);    // logical k-chunk for this phys slot
      gll16(A + (size_t)(m0 + r) * K + k0 + lc * 8, &As[buf][g * 8]);
    }
#pragma unroll
    for (int p = 0; p < TN * 8 / NT; p++) {
      const int g = p * NT + tid;
      const int r = g >> 3;
      const int lc = (g & 7) ^ (r & 7);
      gll16(Bt + (size_t)(n0 + r) * K + k0 + lc * 8, &Bs[buf][g * 8]);
    }
  };

  stage(0, 0);
  __syncthreads();   // implicit vmcnt(0): tile 0 resident
  int cur = 0;

  for (int k0 = 0; k0 < K; k0 += 64) {
    // ---- prefetch next K-tile into the other buffer (issued pre-compute) --
    if (k0 + 64 < K) stage(cur ^ 1, k0 + 64);
    // ---- compute current tile: 2 k-halves of 32 ----
#pragma unroll
    for (int ki = 0; ki < 2; ki++) {
      bf16x8 af[MI], bfr[NI];
#pragma unroll
      for (int mi = 0; mi < MI; mi++) {
        const int r = wm * WM + mi * 16 + lm;
        const int p = (ki * 4 + quad) ^ (lm & 7);
        af[mi] = *reinterpret_cast<const bf16x8*>(&As[cur][r * 64 + p * 8]);
      }
#pragma unroll
      for (int ni = 0; ni < NI; ni++) {
        const int r = wn * WN + ni * 16 + lm;
        const int p = (ki * 4 + quad) ^ (lm & 7);
        bfr[ni] = *reinterpret_cast<const bf16x8*>(&Bs[cur][r * 64 + p * 8]);
      }
#pragma unroll
      for (int mi = 0; mi < MI; mi++)
#pragma unroll
        for (int ni = 0; ni < NI; ni++)
          acc[mi][ni] = __builtin_amdgcn_mfma_f32_16x16x32_bf16(
              af[mi], bfr[ni], acc[mi][ni], 0, 0, 0);
    }
    // one barrier per K-step: readers of buf[cur] done AND (implicit
    // vmcnt(0)) prefetch into buf[cur^1] complete.
    __syncthreads();
    cur ^= 1;
  }

  // ---- epilogue: bias (+silu), C-layout col=lm, row=quad*4+reg ----
#pragma unroll
  for (int ni = 0; ni < NI; ni++) {
    const int n = n0 + wn * WN + ni * 16 + lm;
    const float bv = bias[n];
#pragma unroll
    for (int mi = 0; mi < MI; mi++) {
      const int mbase = m0 + wm * WM + mi * 16 + quad * 4;
#pragma unroll
      for (int reg = 0; reg < 4; reg++) {
        float v = acc[mi][ni][reg] + bv;
        if (EPI_SILU) v = silu_f(v);
        if constexpr (sizeof(OutT) == 2)
          C[(size_t)(mbase + reg) * N + n] = f2bf(v);
        else
          C[(size_t)(mbase + reg) * N + n] = v;
      }
    }
  }
}

// ---------------- fused causal silu-attention, S^T layout, paired qt -------
// att = silu(q k^T + posw[2047+t-s]) * (t<=s);  y = (att @ v) * u
// z row layout (bf16): [u(512) | q(512) | k(512) | v(512)].
// Block: (qt-pair, head, b). Processes q64 tiles qt=blockIdx.x and 15-qt:
// kt-units = (qtA+1)+(qtB+1) = 17 for every block -> perfect balance.
// S^T trick: compute S^T = K Q^T (A=K rows t, B=Q rows s). C-layout gives
// lane (quad,lm): t = tt*16+quad*4+i, s = w*16+lm -> 4 t-consecutive P values
// per lane => us4 ds_write_b64 into Ps[s][t]; PV A-frag = ds_read_b128.
// Q is kept in registers (B-operand frags loaded from global once per tile).
//
// Pipeline: Ks/Vt/bias double-buffered; per kt exactly ONE barrier:
//   [LDS-write buf[kt&1] from regs] -> barrier -> [issue kt+1 global loads
//   into regs] -> [compute from buf[kt&1]].
#define LDR 72   // LDS row stride in u16 (144 B, 16B-aligned, bank-spread)
__global__ __launch_bounds__(256) void attn_kernel(
    const unsigned short* __restrict__ z, const float* __restrict__ posw,
    unsigned short* __restrict__ y) {
  const int hh = blockIdx.y, b = blockIdx.z;
  __shared__ alignas(16) unsigned short Ks[2 * 64 * LDR];
  __shared__ alignas(16) unsigned short Vt[2 * 64 * LDR];
  __shared__ alignas(16) unsigned short Ps[64 * LDR];
  __shared__ float bias_s[2][128];
  const unsigned short* zb = z + (size_t)b * S_LEN * 2048;
  const int tid = threadIdx.x;
  const int w = tid >> 6, lane = tid & 63, lm = lane & 15, quad = lane >> 4;

  // per-thread staging geometry (tid-only, hoisted out of the loops)
  const int kr0r = tid >> 3, kr0c = (tid & 7) * 8;            // K chunk 0
  const int kr1r = (256 + tid) >> 3, kr1c = (tid & 7) * 8;    // K chunk 1
  const int vt = (tid >> 4) * 4, vd = (tid & 15) * 4;         // V 4x4 block
  const int vtb = vt >> 3, vti = vt & 7;

#pragma unroll
  for (int phase = 0; phase < 2; phase++) {
    const int qt = phase == 0 ? (int)blockIdx.x : 15 - (int)blockIdx.x;
    const int s0 = qt * 64;
    const int srow = s0 + w * 16 + lm;   // this lane's q row (as B-operand n)

    // ---- Q fragments in registers (B-operand): Q[srow][ki*32+quad*8 ..+8] --
    const bf16x8 qb0 = *reinterpret_cast<const bf16x8*>(
        zb + (size_t)srow * 2048 + 512 + hh * 64 + quad * 8);
    const bf16x8 qb1 = *reinterpret_cast<const bf16x8*>(
        zb + (size_t)srow * 2048 + 512 + hh * 64 + 32 + quad * 8);

    f32x4 O[4] = {};   // O[s 16][d 64] per wave; col=d-in-tile, row=quad*4+reg

    // staging registers (K tile 2x16B, V 4x4 block, bias scalar)
    us8 kr0, kr1;
    us4 vr0, vr1, vr2, vr3;
    float br = 0.f;

    auto load_stage = [&](int kt) {
      const int t0 = kt * 64;
      kr0 = *reinterpret_cast<const us8*>(
          zb + (size_t)(t0 + kr0r) * 2048 + 1024 + hh * 64 + kr0c);
      kr1 = *reinterpret_cast<const us8*>(
          zb + (size_t)(t0 + kr1r) * 2048 + 1024 + hh * 64 + kr1c);
      vr0 = *reinterpret_cast<const us4*>(
          zb + (size_t)(t0 + vt + 0) * 2048 + 1536 + hh * 64 + vd);
      vr1 = *reinterpret_cast<const us4*>(
          zb + (size_t)(t0 + vt + 1) * 2048 + 1536 + hh * 64 + vd);
      vr2 = *reinterpret_cast<const us4*>(
          zb + (size_t)(t0 + vt + 2) * 2048 + 1536 + hh * 64 + vd);
      vr3 = *reinterpret_cast<const us4*>(
          zb + (size_t)(t0 + vt + 3) * 2048 + 1536 + hh * 64 + vd);
      if (tid < 128) br = posw[2047 + t0 - s0 - 63 + tid];
    };

    auto write_stage = [&](int cur) {
      unsigned short* KsC = Ks + cur * (64 * LDR);
      unsigned short* VtC = Vt + cur * (64 * LDR);
      *reinterpret_cast<us8*>(&KsC[kr0r * LDR + kr0c]) = kr0;
      *reinterpret_cast<us8*>(&KsC[kr1r * LDR + kr1c]) = kr1;
      unsigned short c[4][4];
      c[0][0] = vr0.x; c[0][1] = vr0.y; c[0][2] = vr0.z; c[0][3] = vr0.w;
      c[1][0] = vr1.x; c[1][1] = vr1.y; c[1][2] = vr1.z; c[1][3] = vr1.w;
      c[2][0] = vr2.x; c[2][1] = vr2.y; c[2][2] = vr2.z; c[2][3] = vr2.w;
      c[3][0] = vr3.x; c[3][1] = vr3.y; c[3][2] = vr3.z; c[3][3] = vr3.w;
#pragma unroll
      for (int j = 0; j < 4; j++) {
        const int dd = vd + j;
        us4 o = { c[0][j], c[1][j], c[2][j], c[3][j] };
        *reinterpret_cast<us4*>(&VtC[dd * LDR + ((vtb ^ (dd & 7)) << 3) + vti]) = o;
      }
      if (tid < 128) bias_s[cur][tid] = br;
    };

    load_stage(0);
    __syncthreads();   // phase seam: previous phase's buf readers done

    for (int kt = 0; kt <= qt; kt++) {
      const int cur = kt & 1;
      write_stage(cur);
      __syncthreads();                 // the ONLY barrier per kt
      if (kt < qt) load_stage(kt + 1); // latency hides under compute

      const unsigned short* KsC = Ks + cur * (64 * LDR);
      const unsigned short* VtC = Vt + cur * (64 * LDR);
      const int t0 = kt * 64;

      // ---- S^T = K Q^T : 4 t-tiles x (16 s-cols per wave) ----
#pragma unroll
      for (int tt = 0; tt < 4; tt++) {
        const bf16x8 ka0 = *reinterpret_cast<const bf16x8*>(
            &KsC[(tt * 16 + lm) * LDR + quad * 8]);
        const bf16x8 ka1 = *reinterpret_cast<const bf16x8*>(
            &KsC[(tt * 16 + lm) * LDR + 32 + quad * 8]);
        f32x4 st = {};
        __builtin_amdgcn_s_setprio(1);
        st = __builtin_amdgcn_mfma_f32_16x16x32_bf16(ka0, qb0, st, 0, 0, 0);
        st = __builtin_amdgcn_mfma_f32_16x16x32_bf16(ka1, qb1, st, 0, 0, 0);
        __builtin_amdgcn_s_setprio(0);
        // lane holds t = t0 + tt*16 + quad*4 + i,  s = srow
        const int bbase = 63 + tt * 16 + quad * 4 - w * 16 - lm;  // + i
        const int tq = t0 + tt * 16 + quad * 4;
        us4 pv;
        unsigned short* pp = (unsigned short*)&pv;
#pragma unroll
        for (int i = 0; i < 4; i++) {
          const float x = st[i] + bias_s[cur][bbase + i];
          const float val = (tq + i <= srow) ? silu_f(x) : 0.f;
          pp[i] = f2bf(val);
        }
        // Ps[s][t]: wave-private rows [w*16, w*16+16)
        *reinterpret_cast<us4*>(&Ps[(w * 16 + lm) * LDR + tt * 16 + quad * 4]) = pv;
      }

      // ---- O += P V  (A = Ps stripe, B = Vt) ----
      const bf16x8 pa0 = *reinterpret_cast<const bf16x8*>(
          &Ps[(w * 16 + lm) * LDR + quad * 8]);
      const bf16x8 pa1 = *reinterpret_cast<const bf16x8*>(
          &Ps[(w * 16 + lm) * LDR + 32 + quad * 8]);
#pragma unroll
      for (int ct = 0; ct < 4; ct++) {
        const int d = ct * 16 + lm;
        const bf16x8 vb0 = *reinterpret_cast<const bf16x8*>(
            &VtC[d * LDR + ((quad ^ (d & 7)) << 3)]);            // tb=quad
        const bf16x8 vb1 = *reinterpret_cast<const bf16x8*>(
            &VtC[d * LDR + (((4 + quad) ^ (d & 7)) << 3)]);      // tb=4+quad
        __builtin_amdgcn_s_setprio(1);
        O[ct] = __builtin_amdgcn_mfma_f32_16x16x32_bf16(pa0, vb0, O[ct], 0, 0, 0);
        O[ct] = __builtin_amdgcn_mfma_f32_16x16x32_bf16(pa1, vb1, O[ct], 0, 0, 0);
        __builtin_amdgcn_s_setprio(0);
      }
    }

    // ---- epilogue: y = bf16(O * u) ----
    {
      const int sbase = s0 + w * 16 + quad * 4;
#pragma unroll
      for (int ct = 0; ct < 4; ct++) {
        const int d = ct * 16 + lm;
#pragma unroll
        for (int i = 0; i < 4; i++) {
          const int sg = sbase + i;
          const float u = bf2f(zb[(size_t)sg * 2048 + hh * 64 + d]);
          y[((size_t)(b * S_LEN + sg)) * D_MODEL + hh * 64 + d] = f2bf(O[ct][i] * u);
        }
      }
    }
  }
}

// ---------------- layer norm: one wave per row, templated input ------------
template <typename XT>
__global__ __launch_bounds__(256) void ln_kernel(
    const XT* __restrict__ x, const float* __restrict__ res,
    const float* __restrict__ w, const float* __restrict__ bb,
    float* __restrict__ o32, unsigned short* __restrict__ obf) {
  const int wv = threadIdx.x >> 6, lane = threadIdx.x & 63;
  const size_t row = blockIdx.x * 4 + wv;
  const int c0 = lane * 8;
  float v[8];
  if constexpr (sizeof(XT) == 2) {
    const us8 u = *reinterpret_cast<const us8*>(&x[row * D_MODEL + c0]);
#pragma unroll
    for (int i = 0; i < 8; i++) v[i] = bf2f(u[i]);
  } else {
    const float4 a = *reinterpret_cast<const float4*>(&x[row * D_MODEL + c0]);
    const float4 c = *reinterpret_cast<const float4*>(&x[row * D_MODEL + c0 + 4]);
    v[0] = a.x; v[1] = a.y; v[2] = a.z; v[3] = a.w;
    v[4] = c.x; v[5] = c.y; v[6] = c.z; v[7] = c.w;
  }
  if (res) {
    const float4 r0 = *reinterpret_cast<const float4*>(&res[row * D_MODEL + c0]);
    const float4 r1 = *reinterpret_cast<const float4*>(&res[row * D_MODEL + c0 + 4]);
    v[0] += r0.x; v[1] += r0.y; v[2] += r0.z; v[3] += r0.w;
    v[4] += r1.x; v[5] += r1.y; v[6] += r1.z; v[7] += r1.w;
  }
  float s = 0.f, ss = 0.f;
#pragma unroll
  for (int i = 0; i < 8; i++) { s += v[i]; ss += v[i] * v[i]; }
#pragma unroll
  for (int off = 32; off; off >>= 1) {
    s += __shfl_down(s, off, 64);
    ss += __shfl_down(ss, off, 64);
  }
  s = __shfl(s, 0, 64);
  ss = __shfl(ss, 0, 64);
  const float mu = s * (1.f / D_MODEL);
  const float rstd = rsqrtf(ss * (1.f / D_MODEL) - mu * mu + 1e-5f);
  const float4 w0 = *reinterpret_cast<const float4*>(&w[c0]);
  const float4 w1 = *reinterpret_cast<const float4*>(&w[c0 + 4]);
  const float4 b0 = *reinterpret_cast<const float4*>(&bb[c0]);
  const float4 b1 = *reinterpret_cast<const float4*>(&bb[c0 + 4]);
  float r[8];
  r[0] = (v[0] - mu) * rstd * w0.x + b0.x;
  r[1] = (v[1] - mu) * rstd * w0.y + b0.y;
  r[2] = (v[2] - mu) * rstd * w0.z + b0.z;
  r[3] = (v[3] - mu) * rstd * w0.w + b0.w;
  r[4] = (v[4] - mu) * rstd * w1.x + b1.x;
  r[5] = (v[5] - mu) * rstd * w1.y + b1.y;
  r[6] = (v[6] - mu) * rstd * w1.z + b1.z;
  r[7] = (v[7] - mu) * rstd * w1.w + b1.w;
  if (o32) {
    *reinterpret_cast<float4*>(&o32[row * D_MODEL + c0]) = make_float4(r[0], r[1], r[2], r[3]);
    *reinterpret_cast<float4*>(&o32[row * D_MODEL + c0 + 4]) = make_float4(r[4], r[5], r[6], r[7]);
  }
  if (obf) {
    us8 q = { f2bf(r[0]), f2bf(r[1]), f2bf(r[2]), f2bf(r[3]),
              f2bf(r[4]), f2bf(r[5]), f2bf(r[6]), f2bf(r[7]) };
    *reinterpret_cast<us8*>(&obf[row * D_MODEL + c0]) = q;
  }
}

extern "C" void kernel_launch(void* const* d_in, const int* in_sizes, int n_in,
                              void* d_out, int out_size, void* d_ws, size_t ws_size,
                              hipStream_t stream) {
  const int* hist_i = (const int*)d_in[0];
  const int* hist_c = (const int*)d_in[1];
  const int* hlen   = (const int*)d_in[2];
  const int* tgt_i  = (const int*)d_in[3];
  const int* tgt_c  = (const int*)d_in[4];
  const float* item_emb = (const float*)d_in[5];
  const float* cate_emb = (const float*)d_in[6];
  const float* seg_emb  = (const float*)d_in[7];
  const float* W1   = (const float*)d_in[8];    // [4,512,2048]
  const float* b1   = (const float*)d_in[9];    // [4,2048]
  const float* W2   = (const float*)d_in[10];   // [4,512,512]
  const float* b2   = (const float*)d_in[11];   // [4,512]
  const float* ln1w = (const float*)d_in[12];
  const float* ln1b = (const float*)d_in[13];
  const float* ln2w = (const float*)d_in[14];
  const float* ln2b = (const float*)d_in[15];
  const float* posw = (const float*)d_in[16];   // [4,4095]
  const float* lnfw = (const float*)d_in[17];
  const float* lnfb = (const float*)d_in[18];
  float* out = (float*)d_out;

  char* ws = (char*)d_ws;
  float*          h32 = (float*)(ws);                         // 16 MB
  unsigned short* hbf = (unsigned short*)(ws + (16u << 20));  // 8 MB
  unsigned short* zbf = (unsigned short*)(ws + (24u << 20));  // 32 MB
  unsigned short* ybf = (unsigned short*)(ws + (56u << 20));  // 8 MB
  unsigned short* yab = (unsigned short*)(ws + (64u << 20));  // 8 MB (attn out)
  unsigned short* tbf = yab;                                  // alias: yab dead after LN1
  unsigned short* W1t = (unsigned short*)(ws + (80u << 20));  // 8 MB
  unsigned short* W2t = (unsigned short*)(ws + (88u << 20));  // 2 MB

  const int ROWS = 8 * S_LEN;  // 8192

  transpose_kernel<<<dim3(2048 / 64, 512 / 64, 4), 256, 0, stream>>>(W1, W1t, 512, 2048);
  transpose_kernel<<<dim3(512 / 64, 512 / 64, 4), 256, 0, stream>>>(W2, W2t, 512, 512);
  embed_kernel<<<ROWS, 256, 0, stream>>>(hist_i, hist_c, hlen, tgt_i, tgt_c,
                                         item_emb, cate_emb, seg_emb, h32, hbf);
  for (int l = 0; l < 4; l++) {
    // zbf = silu(h @ W1[l] + b1[l])   [8192, 2048] bf16
    // 128x128 tile, 8 waves (wave tile 64x32), dbuf 64 KB -> 2 blocks/CU
    // = 4 waves/SIMD; XCD swizzle; 1024 blocks.
    mfma_gemm<128, 128, 2, 4, 1, 1, unsigned short><<<1024, 512, 0, stream>>>(
        hbf, W1t + (size_t)l * 2048 * 512, b1 + (size_t)l * 2048, zbf, ROWS, 2048, 512);
    // yab = bf16((silu-att @ v) * u)  [8192, 512]; paired qt, 512 blocks
    attn_kernel<<<dim3(8, NHEADS, 8), 256, 0, stream>>>(
        zbf, posw + (size_t)l * 4095, yab);
    // ybf = LN1(yab)  (bf16 in, bf16 out)
    ln_kernel<unsigned short><<<ROWS / 4, 256, 0, stream>>>(
        yab, nullptr, ln1w + l * 512, ln1b + l * 512, nullptr, ybf);
    // tbf = bf16(ybf @ W2[l] + b2[l])  (aliases yab; yab dead after LN1)
    mfma_gemm<64, 128, 2, 2, 0, 0, unsigned short><<<dim3(512 / 128, ROWS / 64), 256, 0, stream>>>(
        ybf, W2t + (size_t)l * 512 * 512, b2 + (size_t)l * 512, tbf, ROWS, 512, 512);
    // h = LN2(tbf + h)  (f32 + bf16 out)
    ln_kernel<unsigned short><<<ROWS / 4, 256, 0, stream>>>(
        tbf, h32, ln2w + l * 512, ln2b + l * 512, h32, hbf);
  }
  // out = LNf(h)
  ln_kernel<float><<<ROWS / 4, 256, 0, stream>>>(h32, nullptr, lnfw, lnfb, out, nullptr);
}

// Round 6
// 735.322 us; speedup vs baseline: 1.0367x; 1.0123x over previous
//
#include <hip/hip_runtime.h>
#include <cstddef>

// HSTU forward. Round 13: LN1 folded into GEMM2 (algebraic fusion).
//   LN1(y)@W2 + b2 = rs*(y@W2') - rs*mu*c1 + c2 + b2,
//     W2'[k][n] = ln1w[k]*W2[k][n]  (folded in transpose),
//     c1[n] = sum_k ln1w[k]W2[k][n], c2[n] = sum_k ln1b[k]W2[k][n] (c12_kernel).
//   Row stats (mu,rs) of yab computed INSIDE gemm2 from the already-loaded
//   MFMA A-fragments (wn==0 waves, quad-disjoint k coverage, shfl reduce).
//   Deletes LN1 dispatch + ybf intermediate (16 MB/layer traffic).
// GEMM1 (R12 cfg) / attention / LN2 / embed unchanged. R12 = 744.4 us.
//
// ws layout (90 MB):
//   h32  f32  [8192,512]   @ 0      16 MB   residual stream
//   hbf  bf16 [8192,512]   @ 16 MB   8 MB   GEMM1 A input
//   zbf  bf16 [8192,2048]  @ 24 MB  32 MB   u|q|k|v (GEMM1 out, attn in)
//   tbf  bf16 [8192,512]   @ 56 MB   8 MB   GEMM2 out (NO longer aliases yab!)
//   yab  bf16 [8192,512]   @ 64 MB   8 MB   attn out
//   c1/c2 f32 [4,512] each @ 72 MB  16 KB   LN1-fold constants
//   W1t  bf16 [4,2048,512] @ 80 MB   8 MB   transposed bf16 weights
//   W2t  bf16 [4,512,512]  @ 88 MB   2 MB   ln1w-scaled transposed W2

#define D_MODEL 512
#define S_LEN 1024
#define NHEADS 8

typedef __bf16 bf16x8 __attribute__((ext_vector_type(8)));
typedef float f32x4 __attribute__((ext_vector_type(4)));
typedef unsigned short us4 __attribute__((ext_vector_type(4)));
typedef unsigned short us8 __attribute__((ext_vector_type(8)));

__device__ __forceinline__ float silu_f(float x) {
  return x / (1.f + __expf(-x));
}
__device__ __forceinline__ unsigned short f2bf(float f) {
  unsigned int u = __float_as_uint(f);
  u += 0x7FFF + ((u >> 16) & 1);   // round-to-nearest-even
  return (unsigned short)(u >> 16);
}
__device__ __forceinline__ float bf2f(unsigned short s) {
  return __uint_as_float(((unsigned int)s) << 16);
}
__device__ __forceinline__ void gll16(const void* g, void* l) {
  __builtin_amdgcn_global_load_lds(
      (const __attribute__((address_space(1))) unsigned int*)g,
      (__attribute__((address_space(3))) unsigned int*)l, 16, 0, 0);
}

// ---------------- embedding + id construction (dual f32/bf16 write) --------
__global__ __launch_bounds__(256) void embed_kernel(
    const int* __restrict__ hist_i, const int* __restrict__ hist_c,
    const int* __restrict__ hlen, const int* __restrict__ tgt_i,
    const int* __restrict__ tgt_c, const float* __restrict__ item_emb,
    const float* __restrict__ cate_emb, const float* __restrict__ seg_emb,
    float* __restrict__ h32, unsigned short* __restrict__ hbf) {
  int bs = blockIdx.x;            // b*1024 + s
  int b = bs >> 10, s = bs & 1023;
  int l = hlen[b];
  int id, cid, sg;
  if (s == l)       { id = tgt_i[b]; cid = tgt_c[b]; sg = 1; }
  else if (s < 1023){ id = hist_i[b * 1023 + s]; cid = hist_c[b * 1023 + s]; sg = 0; }
  else              { id = 0; cid = 0; sg = 0; }   // pad column
  const float* ie = item_emb + (size_t)id * D_MODEL;
  const float* ce = cate_emb + (size_t)cid * D_MODEL;
  const float* se = seg_emb + (size_t)sg * D_MODEL;
  float* hr = h32 + (size_t)bs * D_MODEL;
  unsigned short* hb = hbf + (size_t)bs * D_MODEL;
  for (int d = threadIdx.x; d < D_MODEL; d += 256) {
    float v = ie[d] + ce[d] + se[d];
    hr[d] = v;
    hb[d] = f2bf(v);
  }
}

// ---------------- weight transpose + fp32->bf16: Wt[n][k] = lnw[k]*W[k][n] --
__global__ __launch_bounds__(256) void transpose_kernel(
    const float* __restrict__ W, unsigned short* __restrict__ Wt,
    int K, int N, const float* __restrict__ lnw) {
  const int l = blockIdx.z;
  W += (size_t)l * K * N;
  Wt += (size_t)l * K * N;
  if (lnw) lnw += (size_t)l * K;
  const int n0 = blockIdx.x * 64, k0 = blockIdx.y * 64;
  __shared__ float T[64][65];
  const int tid = threadIdx.x;
  const int rr = tid >> 4, cc = (tid & 15) * 4;
#pragma unroll
  for (int p = 0; p < 4; p++) {
    const int r = rr + p * 16;
    const float4 v = *reinterpret_cast<const float4*>(&W[(size_t)(k0 + r) * N + n0 + cc]);
    T[r][cc] = v.x; T[r][cc + 1] = v.y; T[r][cc + 2] = v.z; T[r][cc + 3] = v.w;
  }
  __syncthreads();
  float l0 = 1.f, l1 = 1.f, l2 = 1.f, l3 = 1.f;
  if (lnw) { l0 = lnw[k0 + cc]; l1 = lnw[k0 + cc + 1];
             l2 = lnw[k0 + cc + 2]; l3 = lnw[k0 + cc + 3]; }
#pragma unroll
  for (int p = 0; p < 4; p++) {
    const int r = rr + p * 16;       // n within tile
    us4 o = { f2bf(T[cc + 0][r] * l0), f2bf(T[cc + 1][r] * l1),
              f2bf(T[cc + 2][r] * l2), f2bf(T[cc + 3][r] * l3) };
    *reinterpret_cast<us4*>(&Wt[(size_t)(n0 + r) * K + k0 + cc]) = o;
  }
}

// ---------------- c1[n] = sum_k ln1w[k]W2[k][n]; c2 same with ln1b ---------
__global__ __launch_bounds__(256) void c12_kernel(
    const float* __restrict__ W2, const float* __restrict__ ln1w,
    const float* __restrict__ ln1b, float* __restrict__ c1,
    float* __restrict__ c2) {
  const int l = blockIdx.y;
  const int nl = threadIdx.x & 63;
  const int n = blockIdx.x * 64 + nl;
  const int kp = threadIdx.x >> 6;           // 4 parts x 128 k
  const float* W = W2 + (size_t)l * 512 * 512;
  const float* lw = ln1w + (size_t)l * 512;
  const float* lb = ln1b + (size_t)l * 512;
  float s1 = 0.f, s2 = 0.f;
  for (int k = kp * 128; k < kp * 128 + 128; k++) {
    const float wv = W[(size_t)k * 512 + n];
    s1 += lw[k] * wv;
    s2 += lb[k] * wv;
  }
  __shared__ float r1[4][64], r2[4][64];
  r1[kp][nl] = s1;
  r2[kp][nl] = s2;
  __syncthreads();
  if (kp == 0) {
    c1[(size_t)l * 512 + n] = r1[0][nl] + r1[1][nl] + r1[2][nl] + r1[3][nl];
    c2[(size_t)l * 512 + n] = r2[0][nl] + r2[1][nl] + r2[2][nl] + r2[3][nl];
  }
}

// ---------------- bf16 MFMA GEMM: C = epi(A[M,K] @ Bt[N,K]^T + bias) -------
// TMxTN tile, BK=64, WR*WC waves, wave tile (TM/WR)x(TN/WC). LDS: As/Bs
// [2][rows][64] bf16 double-buffered, xor-swizzled 8-elem chunks.
// 2-phase pipeline (R9-proven). SWZ=1: XCD-aware 1D grid decode.
template <int TM, int TN, int WR, int WC, int SWZ, int EPI_SILU, typename OutT>
__global__ __launch_bounds__(WR * WC * 64) void mfma_gemm(
    const unsigned short* __restrict__ A, const unsigned short* __restrict__ Bt,
    const float* __restrict__ bias, OutT* __restrict__ C,
    int M, int N, int K) {
  constexpr int NT = WR * WC * 64;            // threads
  constexpr int WM = TM / WR, WN = TN / WC;   // wave tile
  constexpr int MI = WM / 16, NI = WN / 16;   // 16x16 tiles per wave
  __shared__ unsigned short As[2][TM * 64];
  __shared__ unsigned short Bs[2][TN * 64];
  const int tid = threadIdx.x;
  const int w = tid >> 6, lane = tid & 63, lm = lane & 15, quad = lane >> 4;
  const int wm = w % WR, wn = w / WR;
  int m0, n0;
  if (SWZ) {
    const int id = blockIdx.x;
    const int xcd = id & 7, j = id >> 3;
    const int mPerX = (M / TM) >> 3;
    m0 = (xcd * mPerX + (j % mPerX)) * TM;
    n0 = (j / mPerX) * TN;
  } else {
    m0 = blockIdx.y * TM;
    n0 = blockIdx.x * TN;
  }

  f32x4 acc[MI][NI] = {};

  auto stage = [&](int buf, int k0) {
#pragma unroll
    for (int p = 0; p < TM * 8 / NT; p++) {
      const int g = p * NT + tid;          // 16B chunk id
      const int r = g >> 3;                // tile row
      const int lc = (g & 7) ^ (r & 7);    // logical k-chunk for this phys slot
      gll16(A + (size_t)(m0 + r) * K + k0 + lc * 8, &As[buf][g * 8]);
    }
#pragma unroll
    for (int p = 0; p < TN * 8 / NT; p++) {
      const int g = p * NT + tid;
      const int r = g >> 3;
      const int lc = (g & 7) ^ (r & 7);
      gll16(Bt + (size_t)(n0 + r) * K + k0 + lc * 8, &Bs[buf][g * 8]);
    }
  };

  stage(0, 0);
  __syncthreads();   // implicit vmcnt(0): tile 0 resident
  int cur = 0;

  for (int k0 = 0; k0 < K; k0 += 64) {
    if (k0 + 64 < K) stage(cur ^ 1, k0 + 64);
#pragma unroll
    for (int ki = 0; ki < 2; ki++) {
      bf16x8 af[MI], bfr[NI];
#pragma unroll
      for (int mi = 0; mi < MI; mi++) {
        const int r = wm * WM + mi * 16 + lm;
        const int p = (ki * 4 + quad) ^ (lm & 7);
        af[mi] = *reinterpret_cast<const bf16x8*>(&As[cur][r * 64 + p * 8]);
      }
#pragma unroll
      for (int ni = 0; ni < NI; ni++) {
        const int r = wn * WN + ni * 16 + lm;
        const int p = (ki * 4 + quad) ^ (lm & 7);
        bfr[ni] = *reinterpret_cast<const bf16x8*>(&Bs[cur][r * 64 + p * 8]);
      }
#pragma unroll
      for (int mi = 0; mi < MI; mi++)
#pragma unroll
        for (int ni = 0; ni < NI; ni++)
          acc[mi][ni] = __builtin_amdgcn_mfma_f32_16x16x32_bf16(
              af[mi], bfr[ni], acc[mi][ni], 0, 0, 0);
    }
    __syncthreads();
    cur ^= 1;
  }

  // ---- epilogue: bias (+silu), C-layout col=lm, row=quad*4+reg ----
#pragma unroll
  for (int ni = 0; ni < NI; ni++) {
    const int n = n0 + wn * WN + ni * 16 + lm;
    const float bv = bias[n];
#pragma unroll
    for (int mi = 0; mi < MI; mi++) {
      const int mbase = m0 + wm * WM + mi * 16 + quad * 4;
#pragma unroll
      for (int reg = 0; reg < 4; reg++) {
        float v = acc[mi][ni][reg] + bv;
        if (EPI_SILU) v = silu_f(v);
        if constexpr (sizeof(OutT) == 2)
          C[(size_t)(mbase + reg) * N + n] = f2bf(v);
        else
          C[(size_t)(mbase + reg) * N + n] = v;
      }
    }
  }
}

// ---------------- GEMM2 with LN1 folded in ---------------------------------
// C = bf16( rs*(A@W2') - rs*mu*c1 + c2 + b2 ),  A = raw attn out (bf16).
// 64x128 tile, 4 waves (2x2), wave tile 32x64, 2-phase dbuf (R9 structure).
// LN1 row stats accumulated from the already-loaded MFMA A-fragments:
// wn==0 waves cover rows wm*32+mi*16+lm; quads hold disjoint k-chunks
// (logical chunk ki*4+quad) -> quad shfl-reduce gives full-row sums.
__global__ __launch_bounds__(256) void gemm2_ln1(
    const unsigned short* __restrict__ A, const unsigned short* __restrict__ Bt,
    const float* __restrict__ b2, const float* __restrict__ c1,
    const float* __restrict__ c2, unsigned short* __restrict__ C) {
  constexpr int TM = 64, TN = 128, NT = 256, K = 512, N = 512;
  constexpr int MI = 2, NI = 4;   // wave tile 32x64
  __shared__ unsigned short As[2][TM * 64];
  __shared__ unsigned short Bs[2][TN * 64];
  __shared__ float rsum[64], rssum[64];
  const int tid = threadIdx.x;
  const int w = tid >> 6, lane = tid & 63, lm = lane & 15, quad = lane >> 4;
  const int wm = w & 1, wn = w >> 1;
  const int m0 = blockIdx.y * TM, n0 = blockIdx.x * TN;

  f32x4 acc[MI][NI] = {};
  float sA[MI] = {0.f, 0.f}, ssA[MI] = {0.f, 0.f};

  auto stage = [&](int buf, int k0) {
#pragma unroll
    for (int p = 0; p < 2; p++) {   // A: TM*8/NT = 2
      const int g = p * NT + tid;
      const int r = g >> 3;
      const int lc = (g & 7) ^ (r & 7);
      gll16(A + (size_t)(m0 + r) * K + k0 + lc * 8, &As[buf][g * 8]);
    }
#pragma unroll
    for (int p = 0; p < 4; p++) {   // B: TN*8/NT = 4
      const int g = p * NT + tid;
      const int r = g >> 3;
      const int lc = (g & 7) ^ (r & 7);
      gll16(Bt + (size_t)(n0 + r) * K + k0 + lc * 8, &Bs[buf][g * 8]);
    }
  };

  stage(0, 0);
  __syncthreads();
  int cur = 0;
  for (int k0 = 0; k0 < K; k0 += 64) {
    if (k0 + 64 < K) stage(cur ^ 1, k0 + 64);
#pragma unroll
    for (int ki = 0; ki < 2; ki++) {
      bf16x8 af[MI], bfr[NI];
#pragma unroll
      for (int mi = 0; mi < MI; mi++) {
        const int r = wm * 32 + mi * 16 + lm;
        const int p = (ki * 4 + quad) ^ (lm & 7);
        af[mi] = *reinterpret_cast<const bf16x8*>(&As[cur][r * 64 + p * 8]);
      }
#pragma unroll
      for (int ni = 0; ni < NI; ni++) {
        const int r = wn * 64 + ni * 16 + lm;
        const int p = (ki * 4 + quad) ^ (lm & 7);
        bfr[ni] = *reinterpret_cast<const bf16x8*>(&Bs[cur][r * 64 + p * 8]);
      }
      if (wn == 0) {   // LN1 stats from already-loaded A frags (free reads)
#pragma unroll
        for (int mi = 0; mi < MI; mi++) {
          const us8 u = *reinterpret_cast<const us8*>(&af[mi]);
#pragma unroll
          for (int e = 0; e < 8; e++) {
            const float x = bf2f(u[e]);
            sA[mi] += x;
            ssA[mi] += x * x;
          }
        }
      }
#pragma unroll
      for (int mi = 0; mi < MI; mi++)
#pragma unroll
        for (int ni = 0; ni < NI; ni++)
          acc[mi][ni] = __builtin_amdgcn_mfma_f32_16x16x32_bf16(
              af[mi], bfr[ni], acc[mi][ni], 0, 0, 0);
    }
    __syncthreads();
    cur ^= 1;
  }

  // ---- reduce LN1 stats across quads (disjoint k portions of each row) ----
  if (wn == 0) {
#pragma unroll
    for (int mi = 0; mi < MI; mi++) {
      float s = sA[mi], ss = ssA[mi];
      s += __shfl_xor(s, 16, 64);
      s += __shfl_xor(s, 32, 64);
      ss += __shfl_xor(ss, 16, 64);
      ss += __shfl_xor(ss, 32, 64);
      if (quad == 0) {
        rsum[wm * 32 + mi * 16 + lm] = s;
        rssum[wm * 32 + mi * 16 + lm] = ss;
      }
    }
  }
  __syncthreads();

  // ---- per-thread stats for its 8 output rows ----
  float rs8[MI][4], rm8[MI][4];
#pragma unroll
  for (int mi = 0; mi < MI; mi++)
#pragma unroll
    for (int reg = 0; reg < 4; reg++) {
      const int lr = wm * 32 + mi * 16 + quad * 4 + reg;
      const float mu = rsum[lr] * (1.f / 512.f);
      const float var = rssum[lr] * (1.f / 512.f) - mu * mu;
      const float rs = rsqrtf(var + 1e-5f);
      rs8[mi][reg] = rs;
      rm8[mi][reg] = rs * mu;
    }

  // ---- epilogue: C = rs*G - rs*mu*c1[n] + c2[n] + b2[n] ----
#pragma unroll
  for (int ni = 0; ni < NI; ni++) {
    const int n = n0 + wn * 64 + ni * 16 + lm;
    const float c1v = c1[n];
    const float bv = c2[n] + b2[n];
#pragma unroll
    for (int mi = 0; mi < MI; mi++) {
      const int mbase = m0 + wm * 32 + mi * 16 + quad * 4;
#pragma unroll
      for (int reg = 0; reg < 4; reg++) {
        const float v = rs8[mi][reg] * acc[mi][ni][reg] - rm8[mi][reg] * c1v + bv;
        C[(size_t)(mbase + reg) * N + n] = f2bf(v);
      }
    }
  }
}

// ---------------- fused causal silu-attention, S^T layout, paired qt -------
#define LDR 72   // LDS row stride in u16 (144 B, 16B-aligned, bank-spread)
__global__ __launch_bounds__(256) void attn_kernel(
    const unsigned short* __restrict__ z, const float* __restrict__ posw,
    unsigned short* __restrict__ y) {
  const int hh = blockIdx.y, b = blockIdx.z;
  __shared__ alignas(16) unsigned short Ks[2 * 64 * LDR];
  __shared__ alignas(16) unsigned short Vt[2 * 64 * LDR];
  __shared__ alignas(16) unsigned short Ps[64 * LDR];
  __shared__ float bias_s[2][128];
  const unsigned short* zb = z + (size_t)b * S_LEN * 2048;
  const int tid = threadIdx.x;
  const int w = tid >> 6, lane = tid & 63, lm = lane & 15, quad = lane >> 4;

  const int kr0r = tid >> 3, kr0c = (tid & 7) * 8;            // K chunk 0
  const int kr1r = (256 + tid) >> 3, kr1c = (tid & 7) * 8;    // K chunk 1
  const int vt = (tid >> 4) * 4, vd = (tid & 15) * 4;         // V 4x4 block
  const int vtb = vt >> 3, vti = vt & 7;

#pragma unroll
  for (int phase = 0; phase < 2; phase++) {
    const int qt = phase == 0 ? (int)blockIdx.x : 15 - (int)blockIdx.x;
    const int s0 = qt * 64;
    const int srow = s0 + w * 16 + lm;

    const bf16x8 qb0 = *reinterpret_cast<const bf16x8*>(
        zb + (size_t)srow * 2048 + 512 + hh * 64 + quad * 8);
    const bf16x8 qb1 = *reinterpret_cast<const bf16x8*>(
        zb + (size_t)srow * 2048 + 512 + hh * 64 + 32 + quad * 8);

    f32x4 O[4] = {};

    us8 kr0, kr1;
    us4 vr0, vr1, vr2, vr3;
    float br = 0.f;

    auto load_stage = [&](int kt) {
      const int t0 = kt * 64;
      kr0 = *reinterpret_cast<const us8*>(
          zb + (size_t)(t0 + kr0r) * 2048 + 1024 + hh * 64 + kr0c);
      kr1 = *reinterpret_cast<const us8*>(
          zb + (size_t)(t0 + kr1r) * 2048 + 1024 + hh * 64 + kr1c);
      vr0 = *reinterpret_cast<const us4*>(
          zb + (size_t)(t0 + vt + 0) * 2048 + 1536 + hh * 64 + vd);
      vr1 = *reinterpret_cast<const us4*>(
          zb + (size_t)(t0 + vt + 1) * 2048 + 1536 + hh * 64 + vd);
      vr2 = *reinterpret_cast<const us4*>(
          zb + (size_t)(t0 + vt + 2) * 2048 + 1536 + hh * 64 + vd);
      vr3 = *reinterpret_cast<const us4*>(
          zb + (size_t)(t0 + vt + 3) * 2048 + 1536 + hh * 64 + vd);
      if (tid < 128) br = posw[2047 + t0 - s0 - 63 + tid];
    };

    auto write_stage = [&](int cur) {
      unsigned short* KsC = Ks + cur * (64 * LDR);
      unsigned short* VtC = Vt + cur * (64 * LDR);
      *reinterpret_cast<us8*>(&KsC[kr0r * LDR + kr0c]) = kr0;
      *reinterpret_cast<us8*>(&KsC[kr1r * LDR + kr1c]) = kr1;
      unsigned short c[4][4];
      c[0][0] = vr0.x; c[0][1] = vr0.y; c[0][2] = vr0.z; c[0][3] = vr0.w;
      c[1][0] = vr1.x; c[1][1] = vr1.y; c[1][2] = vr1.z; c[1][3] = vr1.w;
      c[2][0] = vr2.x; c[2][1] = vr2.y; c[2][2] = vr2.z; c[2][3] = vr2.w;
      c[3][0] = vr3.x; c[3][1] = vr3.y; c[3][2] = vr3.z; c[3][3] = vr3.w;
#pragma unroll
      for (int j = 0; j < 4; j++) {
        const int dd = vd + j;
        us4 o = { c[0][j], c[1][j], c[2][j], c[3][j] };
        *reinterpret_cast<us4*>(&VtC[dd * LDR + ((vtb ^ (dd & 7)) << 3) + vti]) = o;
      }
      if (tid < 128) bias_s[cur][tid] = br;
    };

    load_stage(0);
    __syncthreads();   // phase seam: previous phase's buf readers done

    for (int kt = 0; kt <= qt; kt++) {
      const int cur = kt & 1;
      write_stage(cur);
      __syncthreads();                 // the ONLY barrier per kt
      if (kt < qt) load_stage(kt + 1); // latency hides under compute

      const unsigned short* KsC = Ks + cur * (64 * LDR);
      const unsigned short* VtC = Vt + cur * (64 * LDR);
      const int t0 = kt * 64;

#pragma unroll
      for (int tt = 0; tt < 4; tt++) {
        const bf16x8 ka0 = *reinterpret_cast<const bf16x8*>(
            &KsC[(tt * 16 + lm) * LDR + quad * 8]);
        const bf16x8 ka1 = *reinterpret_cast<const bf16x8*>(
            &KsC[(tt * 16 + lm) * LDR + 32 + quad * 8]);
        f32x4 st = {};
        __builtin_amdgcn_s_setprio(1);
        st = __builtin_amdgcn_mfma_f32_16x16x32_bf16(ka0, qb0, st, 0, 0, 0);
        st = __builtin_amdgcn_mfma_f32_16x16x32_bf16(ka1, qb1, st, 0, 0, 0);
        __builtin_amdgcn_s_setprio(0);
        const int bbase = 63 + tt * 16 + quad * 4 - w * 16 - lm;  // + i
        const int tq = t0 + tt * 16 + quad * 4;
        us4 pv;
        unsigned short* pp = (unsigned short*)&pv;
#pragma unroll
        for (int i = 0; i < 4; i++) {
          const float x = st[i] + bias_s[cur][bbase + i];
          const float val = (tq + i <= srow) ? silu_f(x) : 0.f;
          pp[i] = f2bf(val);
        }
        *reinterpret_cast<us4*>(&Ps[(w * 16 + lm) * LDR + tt * 16 + quad * 4]) = pv;
      }

      const bf16x8 pa0 = *reinterpret_cast<const bf16x8*>(
          &Ps[(w * 16 + lm) * LDR + quad * 8]);
      const bf16x8 pa1 = *reinterpret_cast<const bf16x8*>(
          &Ps[(w * 16 + lm) * LDR + 32 + quad * 8]);
#pragma unroll
      for (int ct = 0; ct < 4; ct++) {
        const int d = ct * 16 + lm;
        const bf16x8 vb0 = *reinterpret_cast<const bf16x8*>(
            &VtC[d * LDR + ((quad ^ (d & 7)) << 3)]);            // tb=quad
        const bf16x8 vb1 = *reinterpret_cast<const bf16x8*>(
            &VtC[d * LDR + (((4 + quad) ^ (d & 7)) << 3)]);      // tb=4+quad
        __builtin_amdgcn_s_setprio(1);
        O[ct] = __builtin_amdgcn_mfma_f32_16x16x32_bf16(pa0, vb0, O[ct], 0, 0, 0);
        O[ct] = __builtin_amdgcn_mfma_f32_16x16x32_bf16(pa1, vb1, O[ct], 0, 0, 0);
        __builtin_amdgcn_s_setprio(0);
      }
    }

    // ---- epilogue: y = bf16(O * u) ----
    {
      const int sbase = s0 + w * 16 + quad * 4;
#pragma unroll
      for (int ct = 0; ct < 4; ct++) {
        const int d = ct * 16 + lm;
#pragma unroll
        for (int i = 0; i < 4; i++) {
          const int sg = sbase + i;
          const float u = bf2f(zb[(size_t)sg * 2048 + hh * 64 + d]);
          y[((size_t)(b * S_LEN + sg)) * D_MODEL + hh * 64 + d] = f2bf(O[ct][i] * u);
        }
      }
    }
  }
}

// ---------------- layer norm: one wave per row, templated input ------------
template <typename XT>
__global__ __launch_bounds__(256) void ln_kernel(
    const XT* __restrict__ x, const float* __restrict__ res,
    const float* __restrict__ w, const float* __restrict__ bb,
    float* __restrict__ o32, unsigned short* __restrict__ obf) {
  const int wv = threadIdx.x >> 6, lane = threadIdx.x & 63;
  const size_t row = blockIdx.x * 4 + wv;
  const int c0 = lane * 8;
  float v[8];
  if constexpr (sizeof(XT) == 2) {
    const us8 u = *reinterpret_cast<const us8*>(&x[row * D_MODEL + c0]);
#pragma unroll
    for (int i = 0; i < 8; i++) v[i] = bf2f(u[i]);
  } else {
    const float4 a = *reinterpret_cast<const float4*>(&x[row * D_MODEL + c0]);
    const float4 c = *reinterpret_cast<const float4*>(&x[row * D_MODEL + c0 + 4]);
    v[0] = a.x; v[1] = a.y; v[2] = a.z; v[3] = a.w;
    v[4] = c.x; v[5] = c.y; v[6] = c.z; v[7] = c.w;
  }
  if (res) {
    const float4 r0 = *reinterpret_cast<const float4*>(&res[row * D_MODEL + c0]);
    const float4 r1 = *reinterpret_cast<const float4*>(&res[row * D_MODEL + c0 + 4]);
    v[0] += r0.x; v[1] += r0.y; v[2] += r0.z; v[3] += r0.w;
    v[4] += r1.x; v[5] += r1.y; v[6] += r1.z; v[7] += r1.w;
  }
  float s = 0.f, ss = 0.f;
#pragma unroll
  for (int i = 0; i < 8; i++) { s += v[i]; ss += v[i] * v[i]; }
#pragma unroll
  for (int off = 32; off; off >>= 1) {
    s += __shfl_down(s, off, 64);
    ss += __shfl_down(ss, off, 64);
  }
  s = __shfl(s, 0, 64);
  ss = __shfl(ss, 0, 64);
  const float mu = s * (1.f / D_MODEL);
  const float rstd = rsqrtf(ss * (1.f / D_MODEL) - mu * mu + 1e-5f);
  const float4 w0 = *reinterpret_cast<const float4*>(&w[c0]);
  const float4 w1 = *reinterpret_cast<const float4*>(&w[c0 + 4]);
  const float4 b0 = *reinterpret_cast<const float4*>(&bb[c0]);
  const float4 b1 = *reinterpret_cast<const float4*>(&bb[c0 + 4]);
  float r[8];
  r[0] = (v[0] - mu) * rstd * w0.x + b0.x;
  r[1] = (v[1] - mu) * rstd * w0.y + b0.y;
  r[2] = (v[2] - mu) * rstd * w0.z + b0.z;
  r[3] = (v[3] - mu) * rstd * w0.w + b0.w;
  r[4] = (v[4] - mu) * rstd * w1.x + b1.x;
  r[5] = (v[5] - mu) * rstd * w1.y + b1.y;
  r[6] = (v[6] - mu) * rstd * w1.z + b1.z;
  r[7] = (v[7] - mu) * rstd * w1.w + b1.w;
  if (o32) {
    *reinterpret_cast<float4*>(&o32[row * D_MODEL + c0]) = make_float4(r[0], r[1], r[2], r[3]);
    *reinterpret_cast<float4*>(&o32[row * D_MODEL + c0 + 4]) = make_float4(r[4], r[5], r[6], r[7]);
  }
  if (obf) {
    us8 q = { f2bf(r[0]), f2bf(r[1]), f2bf(r[2]), f2bf(r[3]),
              f2bf(r[4]), f2bf(r[5]), f2bf(r[6]), f2bf(r[7]) };
    *reinterpret_cast<us8*>(&obf[row * D_MODEL + c0]) = q;
  }
}

extern "C" void kernel_launch(void* const* d_in, const int* in_sizes, int n_in,
                              void* d_out, int out_size, void* d_ws, size_t ws_size,
                              hipStream_t stream) {
  const int* hist_i = (const int*)d_in[0];
  const int* hist_c = (const int*)d_in[1];
  const int* hlen   = (const int*)d_in[2];
  const int* tgt_i  = (const int*)d_in[3];
  const int* tgt_c  = (const int*)d_in[4];
  const float* item_emb = (const float*)d_in[5];
  const float* cate_emb = (const float*)d_in[6];
  const float* seg_emb  = (const float*)d_in[7];
  const float* W1   = (const float*)d_in[8];    // [4,512,2048]
  const float* b1   = (const float*)d_in[9];    // [4,2048]
  const float* W2   = (const float*)d_in[10];   // [4,512,512]
  const float* b2   = (const float*)d_in[11];   // [4,512]
  const float* ln1w = (const float*)d_in[12];
  const float* ln1b = (const float*)d_in[13];
  const float* ln2w = (const float*)d_in[14];
  const float* ln2b = (const float*)d_in[15];
  const float* posw = (const float*)d_in[16];   // [4,4095]
  const float* lnfw = (const float*)d_in[17];
  const float* lnfb = (const float*)d_in[18];
  float* out = (float*)d_out;

  char* ws = (char*)d_ws;
  float*          h32 = (float*)(ws);                         // 16 MB
  unsigned short* hbf = (unsigned short*)(ws + (16u << 20));  // 8 MB
  unsigned short* zbf = (unsigned short*)(ws + (24u << 20));  // 32 MB
  unsigned short* tbf = (unsigned short*)(ws + (56u << 20));  // 8 MB (GEMM2 out)
  unsigned short* yab = (unsigned short*)(ws + (64u << 20));  // 8 MB (attn out)
  float*          c1g = (float*)(ws + (72u << 20));           // 8 KB
  float*          c2g = (float*)(ws + (72u << 20) + 8192);    // 8 KB
  unsigned short* W1t = (unsigned short*)(ws + (80u << 20));  // 8 MB
  unsigned short* W2t = (unsigned short*)(ws + (88u << 20));  // 2 MB

  const int ROWS = 8 * S_LEN;  // 8192

  transpose_kernel<<<dim3(2048 / 64, 512 / 64, 4), 256, 0, stream>>>(
      W1, W1t, 512, 2048, nullptr);
  transpose_kernel<<<dim3(512 / 64, 512 / 64, 4), 256, 0, stream>>>(
      W2, W2t, 512, 512, ln1w);                    // W2' = ln1w-scaled
  c12_kernel<<<dim3(8, 4), 256, 0, stream>>>(W2, ln1w, ln1b, c1g, c2g);
  embed_kernel<<<ROWS, 256, 0, stream>>>(hist_i, hist_c, hlen, tgt_i, tgt_c,
                                         item_emb, cate_emb, seg_emb, h32, hbf);
  for (int l = 0; l < 4; l++) {
    // zbf = silu(h @ W1[l] + b1[l])   [8192, 2048] bf16; R12 cfg
    mfma_gemm<128, 128, 2, 4, 1, 1, unsigned short><<<1024, 512, 0, stream>>>(
        hbf, W1t + (size_t)l * 2048 * 512, b1 + (size_t)l * 2048, zbf, ROWS, 2048, 512);
    // yab = bf16((silu-att @ v) * u)  [8192, 512]; paired qt, 512 blocks
    attn_kernel<<<dim3(8, NHEADS, 8), 256, 0, stream>>>(
        zbf, posw + (size_t)l * 4095, yab);
    // tbf = bf16(LN1(yab) @ W2[l] + b2[l])  -- LN1 algebraically folded
    gemm2_ln1<<<dim3(512 / 128, ROWS / 64), 256, 0, stream>>>(
        yab, W2t + (size_t)l * 512 * 512, b2 + (size_t)l * 512,
        c1g + (size_t)l * 512, c2g + (size_t)l * 512, tbf);
    // h = LN2(tbf + h)  (f32 + bf16 out)
    ln_kernel<unsigned short><<<ROWS / 4, 256, 0, stream>>>(
        tbf, h32, ln2w + l * 512, ln2b + l * 512, h32, hbf);
  }
  // out = LNf(h)
  ln_kernel<float><<<ROWS / 4, 256, 0, stream>>>(h32, nullptr, lnfw, lnfb, out, nullptr);
}